// Round 14
// baseline (219.684 us; speedup 1.0000x reference)
//
#include <hip/hip_runtime.h>
#include <math.h>

// Problem constants
#define M_ROWS 32768   // 32*32*32 positions
#define DIMS   256
#define KCODES 4096
#define NTILE  32      // column tiles of 128
#define EPS_C  0.5f    // collection window vs block-row-min (hh err max ~0.1)
#define EPS_R  1.25f   // refine window (covers EPS_C + f16 key rounding)

// ws layout (float units) — base ~2.4 MB; optional candG region (16 MB) if
// ws_size permits (runtime-gated -> refine+gather fusion).
#define WS_CH     0          // 4096*256 halves = 524288 floats (codebook hi f16)
#define WS_V2     524288     // 32768 floats ||v||^2 (fp32-exact)
#define WS_C2     557056     // 4096  floats ||c||^2
#define WS_COLKEY 561152     // 4096  u32 f32-bits colmin (entropy)
#define WS_TOKEN  565248     // 32768 u32 tokens (fallback path only)
#define WS_PART   598016     // 2048 floats per-block mse partials
#define WS_CANDG  606208     // 4194304 u32 candidates (big-ws path only)

// d_out scratch (overwritten by gather at the end):
//   floats [0, 4194304)        : Vh    = 32768*256 f16
//   floats [4194304, 8388608)  : candG fallback location (aliases out ->
//                                forces separate refine kernel; placing candG
//                                anywhere in d_out that out[row] spans races
//                                with other blocks' writes, and placing it in
//                                the Vh region corrupts live A-panels in hh,
//                                so fusion truly requires ws space)

typedef _Float16 half8 __attribute__((ext_vector_type(8)));
typedef _Float16 half4 __attribute__((ext_vector_type(4)));
typedef float floatx4 __attribute__((ext_vector_type(4)));
typedef unsigned uintx4 __attribute__((ext_vector_type(4)));

__device__ inline void glds16(const void* g, void* l) {
  __builtin_amdgcn_global_load_lds(
      (const __attribute__((address_space(1))) void*)g,
      (__attribute__((address_space(3))) void*)l, 16, 0, 0);
}

// ---------------------------------------------------------------------------
// prep: f16-hi conversion of V (-> d_out scratch) and CB (-> ws), exact fp32
// norms, plus colkey init (replaces memset). v14: 16 rows/block (4 per wave)
// -> 2304 blocks instead of 9216: amortizes launch ramp + per-block cost.
__global__ __launch_bounds__(256) void vq_prep(const float* __restrict__ V,
                                               const float* __restrict__ CB,
                                               float* __restrict__ ws,
                                               float* __restrict__ outbuf) {
  if (blockIdx.x < 16)
    ((unsigned*)(ws + WS_COLKEY))[blockIdx.x * 256 + threadIdx.x] = 0xFFFFFFFFu;
  int w = threadIdx.x >> 6, lane = threadIdx.x & 63;
  #pragma unroll
  for (int r = 0; r < 4; ++r) {
    int row = blockIdx.x * 16 + w * 4 + r;
    const float* src;
    _Float16* dst;
    float* nrm;
    if (row < M_ROWS) {
      src = V + (size_t)row * DIMS;
      dst = (_Float16*)outbuf + (size_t)row * DIMS;
      nrm = ws + WS_V2 + row;
    } else {
      int rr = row - M_ROWS;
      src = CB + (size_t)rr * DIMS;
      dst = (_Float16*)(ws + WS_CH) + (size_t)rr * DIMS;
      nrm = ws + WS_C2 + rr;
    }
    float4 v = ((const float4*)src)[lane];
    half4 h;
    h[0] = (_Float16)v.x; h[1] = (_Float16)v.y;
    h[2] = (_Float16)v.z; h[3] = (_Float16)v.w;
    *(half4*)(dst + lane * 4) = h;
    float s = v.x * v.x + v.y * v.y + v.z * v.z + v.w * v.w;
    #pragma unroll
    for (int off = 32; off > 0; off >>= 1) s += __shfl_down(s, off, 64);
    if (lane == 0) *nrm = s;
  }
}

// ---------------------------------------------------------------------------
// hh GEMM: 128x128 tile, 8 waves x (64x32). v14 = v12 structure (v6 + XCD
// swizzle + colkey-atomic hoist) + NONTEMPORAL candG store: candG is written
// once here, read once by refine — NT keeps the 16MB stream from evicting the
// XCD-resident A/B panels (protects the FETCH 67->16.6MB win).
// Design-space ledger: 256x128 tile loses (occ 58->23%), counted-vmcnt loses
// (58->43%), dbuf-prefetch neutral, serial/atomic rowmin loses (conflicts).
__global__ __launch_bounds__(512, 4) void vq_hh(const _Float16* __restrict__ Vh,
                                                const _Float16* __restrict__ Ch,
                                                const float* __restrict__ wsv2,
                                                const float* __restrict__ wsc2,
                                                unsigned* __restrict__ candG,
                                                unsigned* __restrict__ colkey) {
  __shared__ alignas(16) _Float16 Ah[2][128 * 32];   // 16 KB (dbuf)
  __shared__ alignas(16) _Float16 Bh[2][128 * 32];   // 16 KB (dbuf)
  __shared__ float v2s[128];
  __shared__ float c2s[128];
  __shared__ float rowminW[4][128];                  // per-wn partial row mins
  __shared__ float rowminF[128];
  __shared__ unsigned cnt[128];
  __shared__ unsigned candL[128][4];
  __shared__ float colM[2][128];

  const int t = threadIdx.x;                  // 0..511
  const int lane = t & 63, w = t >> 6;        // 8 waves
  const int wm = w & 1, wn = w >> 1;          // wave grid 2x4, each 64 rows x 32 cols
  const int q = lane >> 4, c = lane & 15;
  // XCD-aware swizzle: XCD k (bid%8) gets tiles [k*1024, (k+1)*1024) ->
  // rt in [k*32, (k+1)*32): A-panel stays resident in that XCD's L2.
  const int tile = (blockIdx.x & 7) * 1024 + (blockIdx.x >> 3);
  const int rt = tile >> 5, ct = tile & 31;
  const int rowBase = rt * 128, colBase = ct * 128;

  if (t < 128)      { v2s[t] = wsv2[rowBase + t]; cnt[t] = 0u; }
  else if (t < 256) c2s[t - 128] = wsc2[colBase + (t - 128)];
  ((unsigned*)candL)[t] = 0xFFFFFFFFu;        // 512 entries, one per thread

  floatx4 acc[4][2];
  #pragma unroll
  for (int i = 0; i < 4; ++i)
    #pragma unroll
    for (int j = 0; j < 2; ++j) acc[i][j] = (floatx4){0.f, 0.f, 0.f, 0.f};

  // staging: 512 16B-chunks per operand per buffer, 1 per thread per operand.
  // XOR swizzle: slot (r, jslot) holds k-chunk jslot^((r>>1)&3) of row r.
  const int r0 = t >> 2, j0 = (t & 3) ^ ((r0 >> 1) & 3);
  const _Float16* gA = Vh + (size_t)(rowBase + r0) * DIMS + j0 * 8;
  const _Float16* gB = Ch + (size_t)(colBase + r0) * DIMS + j0 * 8;
  // wave-uniform LDS bases (wave w covers bytes [w*1024, w*1024+1024))
  char* lA = (char*)Ah + w * 1024;
  char* lB = (char*)Bh + w * 1024;
  const int sw = (c >> 1) & 3;                // frag-read swizzle term

  // prologue: stage chunk 0 into buffer 0
  glds16(gA, lA); glds16(gB, lB);
  gA += 32; gB += 32;
  __syncthreads();   // drains prologue stage + covers LDS init

  #pragma unroll
  for (int kc = 0; kc < 8; ++kc) {
    const int cur = kc & 1;
    const int nb = (cur ^ 1) * 8192;          // byte offset of the other buffer
    if (kc < 7) {                             // issue stage(k+1) FIRST
      glds16(gA, lA + nb); glds16(gB, lB + nb);
      gA += 32; gB += 32;
    }
    const _Float16* Ab = Ah[cur];
    const _Float16* Bb = Bh[cur];
    half8 a[4], b[2];
    #pragma unroll
    for (int f = 0; f < 4; ++f) {
      int ra = wm * 64 + f * 16 + c;
      a[f] = *(const half8*)(Ab + ra * 32 + (q ^ sw) * 8);
    }
    #pragma unroll
    for (int f = 0; f < 2; ++f) {
      int rb = wn * 32 + f * 16 + c;
      b[f] = *(const half8*)(Bb + rb * 32 + (q ^ sw) * 8);
    }
    #pragma unroll
    for (int fi = 0; fi < 4; ++fi)
      #pragma unroll
      for (int fj = 0; fj < 2; ++fj)
        acc[fi][fj] = __builtin_amdgcn_mfma_f32_16x16x32_f16(a[fi], b[fj], acc[fi][fj], 0, 0, 0);
    __syncthreads();
  }

  // ---- phase 1: in-place distance transform + halving rowmin + colmin -----
  float cm0 = 3.4e38f, cm1 = 3.4e38f;
  float rv[16];                               // per-lane partial row mins
  const float c2v0 = c2s[wn * 32 + c];
  const float c2v1 = c2s[wn * 32 + 16 + c];
  #pragma unroll
  for (int fi = 0; fi < 4; ++fi) {
    #pragma unroll
    for (int r = 0; r < 4; ++r) {
      int ml = wm * 64 + fi * 16 + q * 4 + r;
      float vv = v2s[ml];
      float d0 = vv + c2v0 - 2.f * acc[fi][0][r];
      float d1 = vv + c2v1 - 2.f * acc[fi][1][r];
      acc[fi][0][r] = d0;
      acc[fi][1][r] = d1;
      cm0 = fminf(cm0, d0);
      cm1 = fminf(cm1, d1);
      rv[fi * 4 + r] = fminf(d0, d1);
    }
  }
  // reduce-scatter min across the 16-lane c-group: 15 shfls, no dependencies
  // between the shfls within a step. After 4 steps lane c owns row brev4(c).
  {
    const int b0 = c & 1;
    #pragma unroll
    for (int k = 0; k < 8; ++k) {
      float send = b0 ? rv[k] : rv[k + 8];
      float recv = __shfl_xor(send, 1, 64);
      rv[k] = fminf(b0 ? rv[k + 8] : rv[k], recv);
    }
    const int b1 = (c >> 1) & 1;
    #pragma unroll
    for (int k = 0; k < 4; ++k) {
      float send = b1 ? rv[k] : rv[k + 4];
      float recv = __shfl_xor(send, 2, 64);
      rv[k] = fminf(b1 ? rv[k + 4] : rv[k], recv);
    }
    const int b2 = (c >> 2) & 1;
    #pragma unroll
    for (int k = 0; k < 2; ++k) {
      float send = b2 ? rv[k] : rv[k + 2];
      float recv = __shfl_xor(send, 4, 64);
      rv[k] = fminf(b2 ? rv[k + 2] : rv[k], recv);
    }
    const int b3 = (c >> 3) & 1;
    {
      float send = b3 ? rv[0] : rv[1];
      float recv = __shfl_xor(send, 8, 64);
      rv[0] = fminf(b3 ? rv[1] : rv[0], recv);
    }
    const int kf = (b0 << 3) | (b1 << 2) | (b2 << 1) | b3;
    rowminW[wn][wm * 64 + (kf >> 2) * 16 + q * 4 + (kf & 3)] = rv[0];
  }
  // colmin: lanes sharing a column differ only in q -> xor 16, 32
  cm0 = fminf(cm0, __shfl_xor(cm0, 16, 64));
  cm0 = fminf(cm0, __shfl_xor(cm0, 32, 64));
  cm1 = fminf(cm1, __shfl_xor(cm1, 16, 64));
  cm1 = fminf(cm1, __shfl_xor(cm1, 32, 64));
  if (lane < 16) {
    colM[wm][wn * 32 + c]      = cm0;
    colM[wm][wn * 32 + 16 + c] = cm1;
  }
  __syncthreads();

  // fold the 4 per-wn partials into the final row min, and ISSUE the colkey
  // atomics here (fire-and-forget): their serialized drain (256 atomics per
  // address device-wide) overlaps phase 2 + candG write instead of being the
  // last exposed op of the block.
  if (t < 128) {
    rowminF[t] = fminf(fminf(rowminW[0][t], rowminW[1][t]),
                       fminf(rowminW[2][t], rowminW[3][t]));
    float cv = fminf(colM[0][t], colM[1][t]);
    atomicMin(&colkey[colBase + t], __float_as_uint(cv));
  }
  __syncthreads();

  // ---- phase 2: collect candidates within rowmin + EPS_C (compare-only) ----
  #pragma unroll
  for (int fi = 0; fi < 4; ++fi) {
    #pragma unroll
    for (int r = 0; r < 4; ++r) {
      int ml = wm * 64 + fi * 16 + q * 4 + r;
      float thresh = rowminF[ml] + EPS_C;
      #pragma unroll
      for (int fj = 0; fj < 2; ++fj) {
        float d = acc[fi][fj][r];
        if (d <= thresh) {
          unsigned pos = atomicAdd(&cnt[ml], 1u);
          if (pos < 4) {
            unsigned short hb = __builtin_bit_cast(unsigned short, (_Float16)d);
            int nl = wn * 32 + fj * 16 + c;
            candL[ml][pos] = ((unsigned)hb << 16) | (unsigned)(colBase + nl);
          }
        }
      }
    }
  }
  __syncthreads();
  if (t < 128) {
    uintx4 cv4 = *(const uintx4*)candL[t];
    __builtin_nontemporal_store(
        cv4, (uintx4*)(candG + ((size_t)(rowBase + t) * NTILE + ct) * 4));
  }
}

// ---------------------------------------------------------------------------
// refine core: per row pick best f16 key; fp64-verify all candidates within
// EPS_R (rare). tok is wave-uniform on return. One wave per row.
// NT loads: candG read exactly once — don't pollute L2 (CB stays resident).
__device__ inline int refine_row(const float* __restrict__ V,
                                 const float* __restrict__ CB,
                                 const unsigned* __restrict__ cg,
                                 int row, int lane) {
  unsigned e0 = __builtin_nontemporal_load(cg + lane);
  unsigned e1 = __builtin_nontemporal_load(cg + lane + 64);
  unsigned m = e0 < e1 ? e0 : e1;
  #pragma unroll
  for (int off = 1; off < 64; off <<= 1) {
    unsigned o = __shfl_xor(m, off, 64);
    m = (o < m) ? o : m;
  }
  float bestv = (float)__builtin_bit_cast(_Float16, (unsigned short)(m >> 16));
  float v0k = (float)__builtin_bit_cast(_Float16, (unsigned short)(e0 >> 16));
  float v1k = (float)__builtin_bit_cast(_Float16, (unsigned short)(e1 >> 16));
  // empty slots (0xFFFF) decode to NaN -> compare false -> excluded
  unsigned long long mask0 = __ballot(v0k <= bestv + EPS_R);
  unsigned long long mask1 = __ballot(v1k <= bestv + EPS_R);
  int tok = (int)(m & 0xFFFFu);
  if (__popcll(mask0) + __popcll(mask1) > 1) {
    float4 x = ((const float4*)(V + (size_t)row * DIMS))[lane];
    double bd = 1e300; int bi = 0x7FFFFFFF;
    #pragma unroll
    for (int h = 0; h < 2; ++h) {
      unsigned long long mask = h ? mask1 : mask0;
      unsigned ee = h ? e1 : e0;
      while (mask) {
        int l = __ffsll((unsigned long long)mask) - 1;
        mask &= mask - 1;
        int idx = (int)(__shfl(ee, l, 64) & 0xFFFFu);
        float4 cv = ((const float4*)(CB + (size_t)idx * DIMS))[lane];
        double dx = (double)cv.x - (double)x.x;
        double dy = (double)cv.y - (double)x.y;
        double dz = (double)cv.z - (double)x.z;
        double dw = (double)cv.w - (double)x.w;
        double s = dx * dx + dy * dy + dz * dz + dw * dw;
        #pragma unroll
        for (int off = 1; off < 64; off <<= 1) s += __shfl_xor(s, off, 64);
        if (s < bd || (s == bd && idx < bi)) { bd = s; bi = idx; }
      }
    }
    tok = bi;
  }
  return tok;
}

// gather core: out = x + (e - x) (nontemporal), per-wave mse partial.
__device__ inline float gather_row(const float* __restrict__ V,
                                   const float* __restrict__ CB,
                                   int tok, int row, int lane,
                                   float* __restrict__ out) {
  float4 e = *(const float4*)(CB + (size_t)tok * DIMS + lane * 4);
  float4 x = *(const float4*)(V + (size_t)row * DIMS + lane * 4);
  float dx = e.x - x.x, dy = e.y - x.y, dz = e.z - x.z, dw = e.w - x.w;
  floatx4 o;
  o[0] = x.x + dx; o[1] = x.y + dy; o[2] = x.z + dz; o[3] = x.w + dw;
  __builtin_nontemporal_store(o, (floatx4*)(out + (size_t)row * DIMS + lane * 4));
  float s = dx * dx + dy * dy + dz * dz + dw * dw;
  #pragma unroll
  for (int off = 32; off > 0; off >>= 1) s += __shfl_down(s, off, 64);
  return s;   // valid on lane 0
}

// ---------------------------------------------------------------------------
// FUSED refine+gather (big-ws path: candG in ws, no aliasing with out).
// v14: 16 rows/block (4 per wave) -> 2048 blocks.
__global__ __launch_bounds__(256) void vq_refgather(const float* __restrict__ V,
                                                    const float* __restrict__ CB,
                                                    const unsigned* __restrict__ candG,
                                                    float* __restrict__ ws,
                                                    float* __restrict__ out) {
  __shared__ float psum[4];
  int w = threadIdx.x >> 6, lane = threadIdx.x & 63;
  float ssum = 0.f;                           // lane-0-valid accumulator
  #pragma unroll
  for (int r = 0; r < 4; ++r) {
    int row = blockIdx.x * 16 + w * 4 + r;
    int tok = refine_row(V, CB, candG + (size_t)row * (NTILE * 4), row, lane);
    ssum += gather_row(V, CB, tok, row, lane, out);
  }
  if (lane == 0) psum[w] = ssum;
  __syncthreads();
  if (threadIdx.x == 0)
    ws[WS_PART + blockIdx.x] = psum[0] + psum[1] + psum[2] + psum[3];
}

// ---------------------------------------------------------------------------
// Fallback path (candG in d_out aliases out -> refine must finish first).
__global__ __launch_bounds__(256) void vq_refine(const float* __restrict__ V,
                                                 const float* __restrict__ CB,
                                                 const unsigned* __restrict__ candG,
                                                 unsigned* __restrict__ token) {
  int w = threadIdx.x >> 6, lane = threadIdx.x & 63;
  #pragma unroll
  for (int r = 0; r < 4; ++r) {
    int row = blockIdx.x * 16 + w * 4 + r;
    int tok = refine_row(V, CB, candG + (size_t)row * (NTILE * 4), row, lane);
    if (lane == 0) token[row] = (unsigned)tok;
  }
}

__global__ __launch_bounds__(256) void vq_gather(const float* __restrict__ V,
                                                 const float* __restrict__ CB,
                                                 const unsigned* __restrict__ token,
                                                 float* __restrict__ ws,
                                                 float* __restrict__ out) {
  __shared__ float psum[4];
  int w = threadIdx.x >> 6, lane = threadIdx.x & 63;
  float ssum = 0.f;
  #pragma unroll
  for (int r = 0; r < 4; ++r) {
    int row = blockIdx.x * 16 + w * 4 + r;
    int tok = (int)token[row];
    ssum += gather_row(V, CB, tok, row, lane, out);
  }
  if (lane == 0) psum[w] = ssum;
  __syncthreads();
  if (threadIdx.x == 0)
    ws[WS_PART + blockIdx.x] = psum[0] + psum[1] + psum[2] + psum[3];
}

// ---------------------------------------------------------------------------
// final: sum 2048 mse partials + 4096 colmins, write loss. One block, 1024 thr.
__global__ __launch_bounds__(1024) void vq_final(const float* __restrict__ ws,
                                                 float* __restrict__ out) {
  __shared__ float psum[16];
  float s = 0.f;
  for (int i = threadIdx.x; i < 2048; i += 1024) s += ws[WS_PART + i];
  const unsigned* ck = (const unsigned*)(ws + WS_COLKEY);
  float cs = 0.f;
  for (int i = threadIdx.x; i < KCODES; i += 1024) cs += __uint_as_float(ck[i]);
  float v = s * (1.25f / 8388608.f) + cs * (0.1f / 4096.f);
  #pragma unroll
  for (int off = 32; off > 0; off >>= 1) v += __shfl_down(v, off, 64);
  int w = threadIdx.x >> 6, lane = threadIdx.x & 63;
  if (lane == 0) psum[w] = v;
  __syncthreads();
  if (threadIdx.x == 0) {
    float acc = 0.f;
    #pragma unroll
    for (int i = 0; i < 16; ++i) acc += psum[i];
    out[8388608] = acc;
  }
}

// ---------------------------------------------------------------------------
extern "C" void kernel_launch(void* const* d_in, const int* in_sizes, int n_in,
                              void* d_out, int out_size, void* d_ws, size_t ws_size,
                              hipStream_t stream) {
  const float* V  = (const float*)d_in[0];   // [32768, 256]
  const float* CB = (const float*)d_in[1];   // [4096, 256]
  float* out = (float*)d_out;                // 8388608 emb + 1 loss
  float* ws  = (float*)d_ws;

  _Float16* Vh     = (_Float16*)out;                 // scratch in d_out
  unsigned* colkey = (unsigned*)(ws + WS_COLKEY);
  unsigned* token  = (unsigned*)(ws + WS_TOKEN);

  // candG placement: ws if it fits (enables refine+gather fusion — no
  // aliasing with out), else d_out upper half (forces separate refine).
  const int big_ws = ws_size >= (size_t)(WS_CANDG + 4194304) * 4;
  unsigned* candG = big_ws ? (unsigned*)(ws + WS_CANDG)
                           : (unsigned*)(out + 4194304);

  vq_prep<<<(M_ROWS + KCODES) / 16, 256, 0, stream>>>(V, CB, ws, out);
  vq_hh<<<8192, 512, 0, stream>>>(Vh, (const _Float16*)(ws + WS_CH),
                                  ws + WS_V2, ws + WS_C2, candG, colkey);
  if (big_ws) {
    vq_refgather<<<M_ROWS / 16, 256, 0, stream>>>(V, CB, candG, ws, out);
  } else {
    vq_refine<<<M_ROWS / 16, 256, 0, stream>>>(V, CB, candG, token);
    vq_gather<<<M_ROWS / 16, 256, 0, stream>>>(V, CB, token, ws, out);
  }
  vq_final<<<1, 1024, 0, stream>>>(ws, out);
}

// Round 15
// 213.192 us; speedup vs baseline: 1.0305x; 1.0305x over previous
//
#include <hip/hip_runtime.h>
#include <math.h>

// Problem constants
#define M_ROWS 32768   // 32*32*32 positions
#define DIMS   256
#define KCODES 4096
#define NTILE  32      // column tiles of 128
#define EPS_C  0.5f    // collection window vs block-row-min (hh err max ~0.1)
#define EPS_R  1.25f   // refine window (covers EPS_C + f16 key rounding)

// ws layout (float units) — base ~2.4 MB; optional candG region (16 MB) if
// ws_size permits (runtime-gated -> refine+gather fusion).
#define WS_CH     0          // 4096*256 halves = 524288 floats (codebook hi f16)
#define WS_V2     524288     // 32768 floats ||v||^2 (fp32-exact)
#define WS_C2     557056     // 4096  floats ||c||^2
#define WS_COLKEY 561152     // 4096  u32 f32-bits colmin (entropy)
#define WS_TOKEN  565248     // 32768 u32 tokens (fallback path only)
#define WS_PART   598016     // 2048 floats per-block mse partials
#define WS_CANDG  606208     // 4194304 u32 candidates (big-ws path only)

// d_out scratch (overwritten by gather at the end):
//   floats [0, 4194304)        : Vh    = 32768*256 f16
//   floats [4194304, 8388608)  : candG fallback location (aliases out ->
//                                forces separate refine kernel)

typedef _Float16 half8 __attribute__((ext_vector_type(8)));
typedef _Float16 half4 __attribute__((ext_vector_type(4)));
typedef float floatx4 __attribute__((ext_vector_type(4)));

__device__ inline void glds16(const void* g, void* l) {
  __builtin_amdgcn_global_load_lds(
      (const __attribute__((address_space(1))) void*)g,
      (__attribute__((address_space(3))) void*)l, 16, 0, 0);
}

// ---------------------------------------------------------------------------
// prep: f16-hi conversion of V (-> d_out scratch) and CB (-> ws), exact fp32
// norms, plus colkey init (replaces memset). v14: 16 rows/block (4 per wave)
// -> 2304 blocks instead of 9216: amortizes launch ramp + per-block cost.
__global__ __launch_bounds__(256) void vq_prep(const float* __restrict__ V,
                                               const float* __restrict__ CB,
                                               float* __restrict__ ws,
                                               float* __restrict__ outbuf) {
  if (blockIdx.x < 16)
    ((unsigned*)(ws + WS_COLKEY))[blockIdx.x * 256 + threadIdx.x] = 0xFFFFFFFFu;
  int w = threadIdx.x >> 6, lane = threadIdx.x & 63;
  #pragma unroll
  for (int r = 0; r < 4; ++r) {
    int row = blockIdx.x * 16 + w * 4 + r;
    const float* src;
    _Float16* dst;
    float* nrm;
    if (row < M_ROWS) {
      src = V + (size_t)row * DIMS;
      dst = (_Float16*)outbuf + (size_t)row * DIMS;
      nrm = ws + WS_V2 + row;
    } else {
      int rr = row - M_ROWS;
      src = CB + (size_t)rr * DIMS;
      dst = (_Float16*)(ws + WS_CH) + (size_t)rr * DIMS;
      nrm = ws + WS_C2 + rr;
    }
    float4 v = ((const float4*)src)[lane];
    half4 h;
    h[0] = (_Float16)v.x; h[1] = (_Float16)v.y;
    h[2] = (_Float16)v.z; h[3] = (_Float16)v.w;
    *(half4*)(dst + lane * 4) = h;
    float s = v.x * v.x + v.y * v.y + v.z * v.z + v.w * v.w;
    #pragma unroll
    for (int off = 32; off > 0; off >>= 1) s += __shfl_down(s, off, 64);
    if (lane == 0) *nrm = s;
  }
}

// ---------------------------------------------------------------------------
// hh GEMM: 128x128 tile, 8 waves x (64x32). v15 = v12 structure (v6 + XCD
// swizzle + colkey-atomic hoist). candG store back to PLAIN CACHED (round-14
// NT store: 16B stores at 512B stride -> 4x write amplification, WRITE
// 20.5->74MB, and refine lost its L2 hit on candG. NT on scattered
// small-granule write-once data is a loss; FETCH was already compulsory).
// Design-space ledger: 256x128 tile loses (occ 58->23%), counted-vmcnt loses
// (58->43%), dbuf-prefetch neutral, serial/atomic rowmin loses (conflicts),
// NT candG loses (write amplification).
__global__ __launch_bounds__(512, 4) void vq_hh(const _Float16* __restrict__ Vh,
                                                const _Float16* __restrict__ Ch,
                                                const float* __restrict__ wsv2,
                                                const float* __restrict__ wsc2,
                                                unsigned* __restrict__ candG,
                                                unsigned* __restrict__ colkey) {
  __shared__ alignas(16) _Float16 Ah[2][128 * 32];   // 16 KB (dbuf)
  __shared__ alignas(16) _Float16 Bh[2][128 * 32];   // 16 KB (dbuf)
  __shared__ float v2s[128];
  __shared__ float c2s[128];
  __shared__ float rowminW[4][128];                  // per-wn partial row mins
  __shared__ float rowminF[128];
  __shared__ unsigned cnt[128];
  __shared__ unsigned candL[128][4];
  __shared__ float colM[2][128];

  const int t = threadIdx.x;                  // 0..511
  const int lane = t & 63, w = t >> 6;        // 8 waves
  const int wm = w & 1, wn = w >> 1;          // wave grid 2x4, each 64 rows x 32 cols
  const int q = lane >> 4, c = lane & 15;
  // XCD-aware swizzle: XCD k (bid%8) gets tiles [k*1024, (k+1)*1024) ->
  // rt in [k*32, (k+1)*32): A-panel stays resident in that XCD's L2.
  const int tile = (blockIdx.x & 7) * 1024 + (blockIdx.x >> 3);
  const int rt = tile >> 5, ct = tile & 31;
  const int rowBase = rt * 128, colBase = ct * 128;

  if (t < 128)      { v2s[t] = wsv2[rowBase + t]; cnt[t] = 0u; }
  else if (t < 256) c2s[t - 128] = wsc2[colBase + (t - 128)];
  ((unsigned*)candL)[t] = 0xFFFFFFFFu;        // 512 entries, one per thread

  floatx4 acc[4][2];
  #pragma unroll
  for (int i = 0; i < 4; ++i)
    #pragma unroll
    for (int j = 0; j < 2; ++j) acc[i][j] = (floatx4){0.f, 0.f, 0.f, 0.f};

  // staging: 512 16B-chunks per operand per buffer, 1 per thread per operand.
  // XOR swizzle: slot (r, jslot) holds k-chunk jslot^((r>>1)&3) of row r.
  const int r0 = t >> 2, j0 = (t & 3) ^ ((r0 >> 1) & 3);
  const _Float16* gA = Vh + (size_t)(rowBase + r0) * DIMS + j0 * 8;
  const _Float16* gB = Ch + (size_t)(colBase + r0) * DIMS + j0 * 8;
  // wave-uniform LDS bases (wave w covers bytes [w*1024, w*1024+1024))
  char* lA = (char*)Ah + w * 1024;
  char* lB = (char*)Bh + w * 1024;
  const int sw = (c >> 1) & 3;                // frag-read swizzle term

  // prologue: stage chunk 0 into buffer 0
  glds16(gA, lA); glds16(gB, lB);
  gA += 32; gB += 32;
  __syncthreads();   // drains prologue stage + covers LDS init

  #pragma unroll
  for (int kc = 0; kc < 8; ++kc) {
    const int cur = kc & 1;
    const int nb = (cur ^ 1) * 8192;          // byte offset of the other buffer
    if (kc < 7) {                             // issue stage(k+1) FIRST
      glds16(gA, lA + nb); glds16(gB, lB + nb);
      gA += 32; gB += 32;
    }
    const _Float16* Ab = Ah[cur];
    const _Float16* Bb = Bh[cur];
    half8 a[4], b[2];
    #pragma unroll
    for (int f = 0; f < 4; ++f) {
      int ra = wm * 64 + f * 16 + c;
      a[f] = *(const half8*)(Ab + ra * 32 + (q ^ sw) * 8);
    }
    #pragma unroll
    for (int f = 0; f < 2; ++f) {
      int rb = wn * 32 + f * 16 + c;
      b[f] = *(const half8*)(Bb + rb * 32 + (q ^ sw) * 8);
    }
    #pragma unroll
    for (int fi = 0; fi < 4; ++fi)
      #pragma unroll
      for (int fj = 0; fj < 2; ++fj)
        acc[fi][fj] = __builtin_amdgcn_mfma_f32_16x16x32_f16(a[fi], b[fj], acc[fi][fj], 0, 0, 0);
    __syncthreads();
  }

  // ---- phase 1: in-place distance transform + halving rowmin + colmin -----
  float cm0 = 3.4e38f, cm1 = 3.4e38f;
  float rv[16];                               // per-lane partial row mins
  const float c2v0 = c2s[wn * 32 + c];
  const float c2v1 = c2s[wn * 32 + 16 + c];
  #pragma unroll
  for (int fi = 0; fi < 4; ++fi) {
    #pragma unroll
    for (int r = 0; r < 4; ++r) {
      int ml = wm * 64 + fi * 16 + q * 4 + r;
      float vv = v2s[ml];
      float d0 = vv + c2v0 - 2.f * acc[fi][0][r];
      float d1 = vv + c2v1 - 2.f * acc[fi][1][r];
      acc[fi][0][r] = d0;
      acc[fi][1][r] = d1;
      cm0 = fminf(cm0, d0);
      cm1 = fminf(cm1, d1);
      rv[fi * 4 + r] = fminf(d0, d1);
    }
  }
  // reduce-scatter min across the 16-lane c-group: 15 shfls, no dependencies
  // between the shfls within a step. After 4 steps lane c owns row brev4(c).
  {
    const int b0 = c & 1;
    #pragma unroll
    for (int k = 0; k < 8; ++k) {
      float send = b0 ? rv[k] : rv[k + 8];
      float recv = __shfl_xor(send, 1, 64);
      rv[k] = fminf(b0 ? rv[k + 8] : rv[k], recv);
    }
    const int b1 = (c >> 1) & 1;
    #pragma unroll
    for (int k = 0; k < 4; ++k) {
      float send = b1 ? rv[k] : rv[k + 4];
      float recv = __shfl_xor(send, 2, 64);
      rv[k] = fminf(b1 ? rv[k + 4] : rv[k], recv);
    }
    const int b2 = (c >> 2) & 1;
    #pragma unroll
    for (int k = 0; k < 2; ++k) {
      float send = b2 ? rv[k] : rv[k + 2];
      float recv = __shfl_xor(send, 4, 64);
      rv[k] = fminf(b2 ? rv[k + 2] : rv[k], recv);
    }
    const int b3 = (c >> 3) & 1;
    {
      float send = b3 ? rv[0] : rv[1];
      float recv = __shfl_xor(send, 8, 64);
      rv[0] = fminf(b3 ? rv[1] : rv[0], recv);
    }
    const int kf = (b0 << 3) | (b1 << 2) | (b2 << 1) | b3;
    rowminW[wn][wm * 64 + (kf >> 2) * 16 + q * 4 + (kf & 3)] = rv[0];
  }
  // colmin: lanes sharing a column differ only in q -> xor 16, 32
  cm0 = fminf(cm0, __shfl_xor(cm0, 16, 64));
  cm0 = fminf(cm0, __shfl_xor(cm0, 32, 64));
  cm1 = fminf(cm1, __shfl_xor(cm1, 16, 64));
  cm1 = fminf(cm1, __shfl_xor(cm1, 32, 64));
  if (lane < 16) {
    colM[wm][wn * 32 + c]      = cm0;
    colM[wm][wn * 32 + 16 + c] = cm1;
  }
  __syncthreads();

  // fold the 4 per-wn partials into the final row min, and ISSUE the colkey
  // atomics here (fire-and-forget): their serialized drain (256 atomics per
  // address device-wide) overlaps phase 2 + candG write instead of being the
  // last exposed op of the block.
  if (t < 128) {
    rowminF[t] = fminf(fminf(rowminW[0][t], rowminW[1][t]),
                       fminf(rowminW[2][t], rowminW[3][t]));
    float cv = fminf(colM[0][t], colM[1][t]);
    atomicMin(&colkey[colBase + t], __float_as_uint(cv));
  }
  __syncthreads();

  // ---- phase 2: collect candidates within rowmin + EPS_C (compare-only) ----
  #pragma unroll
  for (int fi = 0; fi < 4; ++fi) {
    #pragma unroll
    for (int r = 0; r < 4; ++r) {
      int ml = wm * 64 + fi * 16 + q * 4 + r;
      float thresh = rowminF[ml] + EPS_C;
      #pragma unroll
      for (int fj = 0; fj < 2; ++fj) {
        float d = acc[fi][fj][r];
        if (d <= thresh) {
          unsigned pos = atomicAdd(&cnt[ml], 1u);
          if (pos < 4) {
            unsigned short hb = __builtin_bit_cast(unsigned short, (_Float16)d);
            int nl = wn * 32 + fj * 16 + c;
            candL[ml][pos] = ((unsigned)hb << 16) | (unsigned)(colBase + nl);
          }
        }
      }
    }
  }
  __syncthreads();
  if (t < 128)
    *(uint4*)(candG + ((size_t)(rowBase + t) * NTILE + ct) * 4) = *(uint4*)candL[t];
}

// ---------------------------------------------------------------------------
// refine core: per row pick best f16 key; fp64-verify all candidates within
// EPS_R (rare). tok is wave-uniform on return. One wave per row.
__device__ inline int refine_row(const float* __restrict__ V,
                                 const float* __restrict__ CB,
                                 const unsigned* __restrict__ cg,
                                 int row, int lane) {
  unsigned e0 = cg[lane], e1 = cg[lane + 64];
  unsigned m = e0 < e1 ? e0 : e1;
  #pragma unroll
  for (int off = 1; off < 64; off <<= 1) {
    unsigned o = __shfl_xor(m, off, 64);
    m = (o < m) ? o : m;
  }
  float bestv = (float)__builtin_bit_cast(_Float16, (unsigned short)(m >> 16));
  float v0k = (float)__builtin_bit_cast(_Float16, (unsigned short)(e0 >> 16));
  float v1k = (float)__builtin_bit_cast(_Float16, (unsigned short)(e1 >> 16));
  // empty slots (0xFFFF) decode to NaN -> compare false -> excluded
  unsigned long long mask0 = __ballot(v0k <= bestv + EPS_R);
  unsigned long long mask1 = __ballot(v1k <= bestv + EPS_R);
  int tok = (int)(m & 0xFFFFu);
  if (__popcll(mask0) + __popcll(mask1) > 1) {
    float4 x = ((const float4*)(V + (size_t)row * DIMS))[lane];
    double bd = 1e300; int bi = 0x7FFFFFFF;
    #pragma unroll
    for (int h = 0; h < 2; ++h) {
      unsigned long long mask = h ? mask1 : mask0;
      unsigned ee = h ? e1 : e0;
      while (mask) {
        int l = __ffsll((unsigned long long)mask) - 1;
        mask &= mask - 1;
        int idx = (int)(__shfl(ee, l, 64) & 0xFFFFu);
        float4 cv = ((const float4*)(CB + (size_t)idx * DIMS))[lane];
        double dx = (double)cv.x - (double)x.x;
        double dy = (double)cv.y - (double)x.y;
        double dz = (double)cv.z - (double)x.z;
        double dw = (double)cv.w - (double)x.w;
        double s = dx * dx + dy * dy + dz * dz + dw * dw;
        #pragma unroll
        for (int off = 1; off < 64; off <<= 1) s += __shfl_xor(s, off, 64);
        if (s < bd || (s == bd && idx < bi)) { bd = s; bi = idx; }
      }
    }
    tok = bi;
  }
  return tok;
}

// gather core: out = x + (e - x) (nontemporal), per-wave mse partial.
__device__ inline float gather_row(const float* __restrict__ V,
                                   const float* __restrict__ CB,
                                   int tok, int row, int lane,
                                   float* __restrict__ out) {
  float4 e = *(const float4*)(CB + (size_t)tok * DIMS + lane * 4);
  float4 x = *(const float4*)(V + (size_t)row * DIMS + lane * 4);
  float dx = e.x - x.x, dy = e.y - x.y, dz = e.z - x.z, dw = e.w - x.w;
  floatx4 o;
  o[0] = x.x + dx; o[1] = x.y + dy; o[2] = x.z + dz; o[3] = x.w + dw;
  __builtin_nontemporal_store(o, (floatx4*)(out + (size_t)row * DIMS + lane * 4));
  float s = dx * dx + dy * dy + dz * dz + dw * dw;
  #pragma unroll
  for (int off = 32; off > 0; off >>= 1) s += __shfl_down(s, off, 64);
  return s;   // valid on lane 0
}

// ---------------------------------------------------------------------------
// FUSED refine+gather (big-ws path: candG in ws, no aliasing with out).
// 16 rows/block (4 per wave) -> 2048 blocks.
__global__ __launch_bounds__(256) void vq_refgather(const float* __restrict__ V,
                                                    const float* __restrict__ CB,
                                                    const unsigned* __restrict__ candG,
                                                    float* __restrict__ ws,
                                                    float* __restrict__ out) {
  __shared__ float psum[4];
  int w = threadIdx.x >> 6, lane = threadIdx.x & 63;
  float ssum = 0.f;                           // lane-0-valid accumulator
  #pragma unroll
  for (int r = 0; r < 4; ++r) {
    int row = blockIdx.x * 16 + w * 4 + r;
    int tok = refine_row(V, CB, candG + (size_t)row * (NTILE * 4), row, lane);
    ssum += gather_row(V, CB, tok, row, lane, out);
  }
  if (lane == 0) psum[w] = ssum;
  __syncthreads();
  if (threadIdx.x == 0)
    ws[WS_PART + blockIdx.x] = psum[0] + psum[1] + psum[2] + psum[3];
}

// ---------------------------------------------------------------------------
// Fallback path (candG in d_out aliases out -> refine must finish first).
__global__ __launch_bounds__(256) void vq_refine(const float* __restrict__ V,
                                                 const float* __restrict__ CB,
                                                 const unsigned* __restrict__ candG,
                                                 unsigned* __restrict__ token) {
  int w = threadIdx.x >> 6, lane = threadIdx.x & 63;
  #pragma unroll
  for (int r = 0; r < 4; ++r) {
    int row = blockIdx.x * 16 + w * 4 + r;
    int tok = refine_row(V, CB, candG + (size_t)row * (NTILE * 4), row, lane);
    if (lane == 0) token[row] = (unsigned)tok;
  }
}

__global__ __launch_bounds__(256) void vq_gather(const float* __restrict__ V,
                                                 const float* __restrict__ CB,
                                                 const unsigned* __restrict__ token,
                                                 float* __restrict__ ws,
                                                 float* __restrict__ out) {
  __shared__ float psum[4];
  int w = threadIdx.x >> 6, lane = threadIdx.x & 63;
  float ssum = 0.f;
  #pragma unroll
  for (int r = 0; r < 4; ++r) {
    int row = blockIdx.x * 16 + w * 4 + r;
    int tok = (int)token[row];
    ssum += gather_row(V, CB, tok, row, lane, out);
  }
  if (lane == 0) psum[w] = ssum;
  __syncthreads();
  if (threadIdx.x == 0)
    ws[WS_PART + blockIdx.x] = psum[0] + psum[1] + psum[2] + psum[3];
}

// ---------------------------------------------------------------------------
// final: sum 2048 mse partials + 4096 colmins, write loss. One block, 1024 thr.
__global__ __launch_bounds__(1024) void vq_final(const float* __restrict__ ws,
                                                 float* __restrict__ out) {
  __shared__ float psum[16];
  float s = 0.f;
  for (int i = threadIdx.x; i < 2048; i += 1024) s += ws[WS_PART + i];
  const unsigned* ck = (const unsigned*)(ws + WS_COLKEY);
  float cs = 0.f;
  for (int i = threadIdx.x; i < KCODES; i += 1024) cs += __uint_as_float(ck[i]);
  float v = s * (1.25f / 8388608.f) + cs * (0.1f / 4096.f);
  #pragma unroll
  for (int off = 32; off > 0; off >>= 1) v += __shfl_down(v, off, 64);
  int w = threadIdx.x >> 6, lane = threadIdx.x & 63;
  if (lane == 0) psum[w] = v;
  __syncthreads();
  if (threadIdx.x == 0) {
    float acc = 0.f;
    #pragma unroll
    for (int i = 0; i < 16; ++i) acc += psum[i];
    out[8388608] = acc;
  }
}

// ---------------------------------------------------------------------------
extern "C" void kernel_launch(void* const* d_in, const int* in_sizes, int n_in,
                              void* d_out, int out_size, void* d_ws, size_t ws_size,
                              hipStream_t stream) {
  const float* V  = (const float*)d_in[0];   // [32768, 256]
  const float* CB = (const float*)d_in[1];   // [4096, 256]
  float* out = (float*)d_out;                // 8388608 emb + 1 loss
  float* ws  = (float*)d_ws;

  _Float16* Vh     = (_Float16*)out;                 // scratch in d_out
  unsigned* colkey = (unsigned*)(ws + WS_COLKEY);
  unsigned* token  = (unsigned*)(ws + WS_TOKEN);

  // candG placement: ws if it fits (enables refine+gather fusion — no
  // aliasing with out), else d_out upper half (forces separate refine).
  const int big_ws = ws_size >= (size_t)(WS_CANDG + 4194304) * 4;
  unsigned* candG = big_ws ? (unsigned*)(ws + WS_CANDG)
                           : (unsigned*)(out + 4194304);

  vq_prep<<<(M_ROWS + KCODES) / 16, 256, 0, stream>>>(V, CB, ws, out);
  vq_hh<<<8192, 512, 0, stream>>>(Vh, (const _Float16*)(ws + WS_CH),
                                  ws + WS_V2, ws + WS_C2, candG, colkey);
  if (big_ws) {
    vq_refgather<<<M_ROWS / 16, 256, 0, stream>>>(V, CB, candG, ws, out);
  } else {
    vq_refine<<<M_ROWS / 16, 256, 0, stream>>>(V, CB, candG, token);
    vq_gather<<<M_ROWS / 16, 256, 0, stream>>>(V, CB, token, ws, out);
  }
  vq_final<<<1, 1024, 0, stream>>>(ws, out);
}